// Round 2
// 109.843 us; speedup vs baseline: 1.0020x; 1.0020x over previous
//
#include <hip/hip_runtime.h>
#include <math.h>

constexpr int Bn = 64;
constexpr int Dn = 1024;
constexpr float LOG2E = 1.4426950408889634f;
constexpr float LN2   = 0.6931471805599453f;

__device__ __forceinline__ float exp2_fast(float v) {
#if defined(__has_builtin)
#if __has_builtin(__builtin_amdgcn_exp2f)
  return __builtin_amdgcn_exp2f(v);
#else
  return exp2f(v);
#endif
#else
  return exp2f(v);
#endif
}

// ---------------------------------------------------------------------------
// K_SORTSOFT: fused bucket-sort + analytic Bsum + softsort (former k0 + k2).
// grid = 64 b x 16 rc = 1024 blocks of 256.  Each block re-derives its b's
// bucket sort entirely in LDS (duplicated 16x, but parallel across all CUs:
// ~1.5us of redundant work buys the removal of one launch boundary, the k0
// kernel's wall time, and the pairs/desc global round-trip).
// Sort: bucket via sigmoid(1.702x) ~ Phi(x) -> near-uniform 64 buckets;
// Bsum = x*(Nlo-Nhi)+(Shi-Slo)+sum_{same bucket}|x-x_k|  (exact, any
// intra-bucket permutation).  Descriptors per group of 8 sorted positions:
// exact (a,c) of the group's min-x/max-x elements (concave endpoint bound).
// Softsort phase identical to old k2 but pair/desc loads are wave-uniform
// LDS broadcasts (conflict-free) instead of global float2/float4 loads.
// Zeroes d_out (block 0) for the TAIL layer's atomicAdds.
// ---------------------------------------------------------------------------
__global__ __launch_bounds__(256) void k_sortsoft(
    const float* __restrict__ x, float* __restrict__ xs_out,
    float* __restrict__ out) {
  __shared__ float  xs_[Dn];
  __shared__ float2 prs_[Dn];            // {x*log2e, -Bsum*log2e}
  __shared__ int    bkt_[Dn];
  __shared__ float4 desc_[128];
  __shared__ int   cnt[64], base_[64], off_[64];
  __shared__ float Ssum[64], cN[64], cS[64];
  __shared__ float redM[4][64], redE[4][64], redD[4][64];

  int b   = blockIdx.x >> 4;
  int rc  = blockIdx.x & 15;
  int tid = threadIdx.x;

  if (tid < 64) { cnt[tid] = 0; off_[tid] = 0; Ssum[tid] = 0.f; }
  if (blockIdx.x == 0 && tid < 128) out[tid] = 0.f;
  __syncthreads();

  // ---- bucket count ----
  float4 v4 = *(const float4*)(x + b * Dn + tid * 4);
  float xv[4] = {v4.x, v4.y, v4.z, v4.w};
  int bk[4];
#pragma unroll
  for (int u = 0; u < 4; ++u) {
    float z = exp2_fast(-2.455532f * xv[u]);   // 2^{-1.702 x log2e}, monotone
    float p = 1.f / (1.f + z);                 // ~Phi(x): near-uniform buckets
    int t = (int)(p * 64.f);
    bk[u] = t < 0 ? 0 : (t > 63 ? 63 : t);
    atomicAdd(&cnt[bk[u]], 1);
    atomicAdd(&Ssum[bk[u]], xv[u]);
  }
  __syncthreads();

  // ---- dual prefix scan (wave 0) ----
  if (tid < 64) {
    int c = cnt[tid]; int si = c;
    float fs = Ssum[tid]; float ss = fs;
#pragma unroll
    for (int d = 1; d < 64; d <<= 1) {
      int oi = __shfl_up(si, d, 64);
      float os = __shfl_up(ss, d, 64);
      if (tid >= d) { si += oi; ss += os; }
    }
    base_[tid] = si - c;                       // Nlo (exclusive)
    float Stot = __shfl(ss, 63, 64);
    float Slo = ss - fs;                       // exclusive sum prefix
    cN[tid] = (float)(2 * (si - c) + c - Dn);  // Nlo - Nhi
    cS[tid] = Stot - 2.f * Slo - fs;           // Shi - Slo
  }
  __syncthreads();

  // ---- scatter ----
#pragma unroll
  for (int u = 0; u < 4; ++u) {
    int pos = base_[bk[u]] + atomicAdd(&off_[bk[u]], 1);
    xs_[pos] = xv[u];
    bkt_[pos] = bk[u];
  }
  __syncthreads();

  // ---- exact Bsum per position ----
#pragma unroll
  for (int r = 0; r < 4; ++r) {
    int p = r * 256 + tid;
    float xp = xs_[p];
    int q = bkt_[p];
    int lo = base_[q], hi = lo + cnt[q];
    float local = 0.f;
    for (int k = lo; k < hi; ++k) local += fabsf(xp - xs_[k]);
    float Bs = fmaf(xp, cN[q], cS[q]) + local;
    prs_[p] = make_float2(xp * LOG2E, -Bs * LOG2E);
  }
  __syncthreads();

  // ---- group descriptors (one group of 8 per thread, 128 groups) ----
  if (tid < 128) {
    int base = tid * 8;
    float xlo = xs_[base], xhi = xlo;
    int ilo = base, ihi = base;
#pragma unroll
    for (int k = 1; k < 8; ++k) {
      float xx = xs_[base + k];
      if (xx < xlo) { xlo = xx; ilo = base + k; }
      if (xx > xhi) { xhi = xx; ihi = base + k; }
    }
    float2 plo = prs_[ilo], phi = prs_[ihi];
    desc_[tid] = make_float4(plo.x, plo.y, phi.x, phi.y);
  }
  __syncthreads();

  // ---- softsort: lane = row; 4 waves own interleaved groups g = 4q+w ----
  int w = tid >> 6, lane = tid & 63;
  int i = rc * 64 + lane;
  float sc = (float)(Dn - 1 - 2 * i);          // exact in fp32
  float gm[32];
  float m = -3.4e38f;
#pragma unroll 8
  for (int q = 0; q < 32; ++q) {
    float4 d = desc_[q * 4 + w];               // wave-uniform broadcast
    float t0 = fmaf(sc, d.x, d.y);             // T at group's min-x element
    float t1 = fmaf(sc, d.z, d.w);             // T at group's max-x element
    float g = fmaxf(t0, t1);
    gm[q] = g;
    m = fmaxf(m, g);
  }
  redM[w][lane] = m;
  __syncthreads();
  float M = fmaxf(fmaxf(redM[0][lane], redM[1][lane]),
                  fmaxf(redM[2][lane], redM[3][lane]));
  float thresh = M - 32.f;

  float se = 0.f, sd = 0.f;
#pragma unroll 4
  for (int q = 0; q < 32; ++q) {
    if (__any(gm[q] > thresh)) {
      int base = (q * 4 + w) * 8;
#pragma unroll
      for (int u = 0; u < 8; ++u) {
        float2 v = prs_[base + u];             // wave-uniform broadcast
        float e = exp2_fast(fmaf(sc, v.x, v.y - M));
        se += e;
        sd = fmaf(e, v.x, sd);
      }
    }
  }
  redE[w][lane] = se;
  redD[w][lane] = sd;
  __syncthreads();
  if (tid < 64) {
    float SE = (redE[0][lane] + redE[1][lane]) + (redE[2][lane] + redE[3][lane]);
    float SD = (redD[0][lane] + redD[1][lane]) + (redD[2][lane] + redD[3][lane]);
    xs_out[b * Dn + rc * 64 + lane] = SD / SE * LN2;
  }
}

// ---------------------------------------------------------------------------
// K3/K4: h = leaky(in @ W^T + bias).  Block = 8 batches x 8 cols; thread
// tile = 1 batch x 4 cols x K/16.  grid = 1024 blocks.
// XCD-aware swizzle: xcd = blk&7 owns a contiguous 16-chunk nc range
// (512 KB of W, resident in that XCD's 4 MiB L2 across its 8 bc-blocks)
// -> ~8x less L3 W traffic.  Heuristic only; correctness placement-free.
// TAIL fuses layer 3 into atomicAdds on d_out (zeroed by k_sortsoft).
// ---------------------------------------------------------------------------
template <bool TAIL>
__global__ __launch_bounds__(256) void layer_kernel(
    const float* __restrict__ in, const float* __restrict__ W,
    const float* __restrict__ bias, float* __restrict__ out,
    const float* __restrict__ W3, const float* __restrict__ b3,
    float* __restrict__ out2) {
  __shared__ float s[8][Dn + 4];
  __shared__ float red[8][8][16];          // [bl][nl][kc]
  __shared__ float r2[8][8][2];
  int xcd = blockIdx.x & 7;
  int idx = blockIdx.x >> 3;               // 0..127
  int nc = xcd * 16 + (idx & 15);          // col chunk 0..127
  int bc = idx >> 4;                       // batch chunk 0..7
  int tid = threadIdx.x;
  const float* src = in + bc * 8 * Dn;
#pragma unroll
  for (int u = 0; u < 8; ++u) {
    int idx2 = (u * 256 + tid) << 2;
    *(float4*)&s[idx2 >> 10][idx2 & 1023] = *(const float4*)(src + idx2);
  }
  __syncthreads();

  int bl = tid & 7;                        // local batch
  int nq = (tid >> 3) & 1;                 // col quad 0..1
  int kc = tid >> 4;                       // k chunk 0..15 (64 elems)
  int n0 = nc * 8 + nq * 4;
  const float* a  = &s[bl][kc * 64];
  const float* w0 = W + (size_t)(n0 + 0) * Dn + kc * 64;
  const float* w1 = W + (size_t)(n0 + 1) * Dn + kc * 64;
  const float* w2 = W + (size_t)(n0 + 2) * Dn + kc * 64;
  const float* w3 = W + (size_t)(n0 + 3) * Dn + kc * 64;
  float a0 = 0.f, a1 = 0.f, a2 = 0.f, a3 = 0.f;
#pragma unroll 4
  for (int kq = 0; kq < 16; ++kq) {
    float4 av = *(const float4*)(a + kq * 4);
    float4 b0 = *(const float4*)(w0 + kq * 4);
    float4 b1 = *(const float4*)(w1 + kq * 4);
    float4 b2 = *(const float4*)(w2 + kq * 4);
    float4 b3v = *(const float4*)(w3 + kq * 4);
    a0 = fmaf(av.x, b0.x, fmaf(av.y, b0.y, fmaf(av.z, b0.z, fmaf(av.w, b0.w, a0))));
    a1 = fmaf(av.x, b1.x, fmaf(av.y, b1.y, fmaf(av.z, b1.z, fmaf(av.w, b1.w, a1))));
    a2 = fmaf(av.x, b2.x, fmaf(av.y, b2.y, fmaf(av.z, b2.z, fmaf(av.w, b2.w, a2))));
    a3 = fmaf(av.x, b3v.x, fmaf(av.y, b3v.y, fmaf(av.z, b3v.z, fmaf(av.w, b3v.w, a3))));
  }
  red[bl][nq * 4 + 0][kc] = a0;
  red[bl][nq * 4 + 1][kc] = a1;
  red[bl][nq * 4 + 2][kc] = a2;
  red[bl][nq * 4 + 3][kc] = a3;
  __syncthreads();

  if (!TAIL) {
    if (tid < 64) {
      int bl2 = tid >> 3, nl2 = tid & 7;
      int n2 = nc * 8 + nl2;
      float hs = 0.f;
#pragma unroll
      for (int q = 0; q < 16; ++q) hs += red[bl2][nl2][q];
      float h = hs + bias[n2];
      h = h >= 0.f ? h : 0.01f * h;
      out[(bc * 8 + bl2) * Dn + n2] = h;
    }
  } else {
    if (tid < 64) {
      int bl2 = tid >> 3, nl2 = tid & 7;
      int n2 = nc * 8 + nl2;
      float hs = 0.f;
#pragma unroll
      for (int q = 0; q < 16; ++q) hs += red[bl2][nl2][q];
      float h = hs + bias[n2];
      h = h >= 0.f ? h : 0.01f * h;
      r2[bl2][nl2][0] = h * W3[n2];
      r2[bl2][nl2][1] = h * W3[Dn + n2];
    }
    __syncthreads();
    if (tid < 16) {
      int bl2 = tid >> 1, o = tid & 1;
      float t = 0.f;
#pragma unroll
      for (int q = 0; q < 8; ++q) t += r2[bl2][q][o];
      if (nc == 0) t += b3[o];
      atomicAdd(out2 + (bc * 8 + bl2) * 2 + o, t);
    }
  }
}

extern "C" void kernel_launch(void* const* d_in, const int* in_sizes, int n_in,
                              void* d_out, int out_size, void* d_ws, size_t ws_size,
                              hipStream_t stream) {
  const float* x  = (const float*)d_in[0];
  const float* W1 = (const float*)d_in[1];
  const float* b1 = (const float*)d_in[2];
  const float* W2 = (const float*)d_in[3];
  const float* b2 = (const float*)d_in[4];
  const float* W3 = (const float*)d_in[5];
  const float* b3 = (const float*)d_in[6];
  float* out = (float*)d_out;
  float* ws = (float*)d_ws;

  float* xs = ws;                // 64*1024 floats = 256 KB
  float* h1 = xs + Bn * Dn;      // 256 KB

  k_sortsoft<<<Bn * 16, 256, 0, stream>>>(x, xs, out);
  layer_kernel<false><<<1024, 256, 0, stream>>>(xs, W1, b1, h1,
                                                nullptr, nullptr, nullptr);
  layer_kernel<true><<<1024, 256, 0, stream>>>(h1, W2, b2, nullptr,
                                               W3, b3, out);
}